// Round 6
// baseline (532.654 us; speedup 1.0000x reference)
//
#include <hip/hip_runtime.h>

static constexpr int NN = 100000;   // nodes
static constexpr int NE = 1600000;  // edges
static constexpr int C  = 128;      // feature dim
static constexpr int OC = 10;       // output classes
static constexpr int NG = 512;      // graphs

// Bucketed CSR build parameters
static constexpr int BSH  = 9;                         // 512 nodes per bucket
static constexpr int BNW  = 1 << BSH;                  // 512
static constexpr int BK   = (NN + BNW - 1) / BNW;      // 196 buckets
static constexpr int NODR = BK * BNW;                  // 100352 (padded node count)
static constexpr int BCAP = 12288;                     // slab capacity (avg ~8163)
static constexpr int EPB  = 8192;                      // edges per binA block
static constexpr int ABLK = (NE + EPB - 1) / EPB;      // 196
static constexpr int NSL  = 8;                         // src slices (src>>14 -> 0..6)

typedef unsigned short u16;
typedef __attribute__((ext_vector_type(8))) short short8;   // 8 bf16 = 16B
typedef __attribute__((ext_vector_type(8))) short bf16x8;   // MFMA A/B frag
typedef __attribute__((ext_vector_type(4))) float f32x4;    // MFMA C/D frag

__device__ __forceinline__ float bf2f(u16 u) {
    union { float f; unsigned int u32; } v; v.u32 = ((unsigned int)u) << 16; return v.f;
}
__device__ __forceinline__ u16 f2bf(float f) {
    union { float f; unsigned int u; } v; v.f = f;
    unsigned int u = v.u;
    unsigned int r = u + 0x7FFF + ((u >> 16) & 1);   // RNE
    return (u16)(r >> 16);
}

// ---------------------------------------------------------------------------
// Phase A: bin edges into BK buckets by dst>>BSH (L2-local slab writes).
// ---------------------------------------------------------------------------
__global__ __launch_bounds__(256) void k_binA(const int* __restrict__ src,
                                              const int* __restrict__ dst,
                                              int* __restrict__ gcnt,
                                              int* __restrict__ buck) {
    __shared__ int cnt[BK];
    __shared__ int curs[BK];
    int tid = threadIdx.x;
    for (int i = tid; i < BK; i += 256) cnt[i] = 0;
    __syncthreads();
    int e0 = blockIdx.x * EPB;
    for (int i = tid; i < EPB; i += 256) {
        int e = e0 + i;
        if (e < NE) atomicAdd(&cnt[dst[e] >> BSH], 1);
    }
    __syncthreads();
    for (int i = tid; i < BK; i += 256) {
        int c = cnt[i];
        int gb = (c > 0) ? atomicAdd(&gcnt[i], c) : 0;
        curs[i] = i * BCAP + gb;
    }
    __syncthreads();
    for (int i = tid; i < EPB; i += 256) {
        int e = e0 + i;
        if (e < NE) {
            int d = dst[e];
            int b = d >> BSH;
            int p = atomicAdd(&curs[b], 1);
            if (p < (b + 1) * BCAP)
                buck[p] = (src[e] << BSH) | (d & (BNW - 1));
        }
    }
}

// ---------------------------------------------------------------------------
// Exclusive scan of bucket counts -> per-bucket CSR base.  Also rp[NN]=NE.
// ---------------------------------------------------------------------------
__global__ void k_binscan(const int* __restrict__ gcnt, int* __restrict__ csrbase,
                          int* __restrict__ rp) {
    __shared__ int buf[256];
    int tid = threadIdx.x;
    int v = (tid < BK) ? gcnt[tid] : 0;
    buf[tid] = v;
    __syncthreads();
    for (int off = 1; off < 256; off <<= 1) {
        int t = (tid >= off) ? buf[tid - off] : 0;
        __syncthreads();
        buf[tid] += t;
        __syncthreads();
    }
    if (tid < BK) csrbase[tid] = buf[tid] - v;
    if (tid == 0) rp[NN] = NE;
}

// ---------------------------------------------------------------------------
// Phase B: one block per bucket.
//  (1) counting-sort bucket edges by (dst_local, src>>14) -> slice-ordered
//      neighbor lists (moving-window L2 locality during gather)
//  (2) emit rp slice
//  (3) counting-sort bucket nodes by degree -> nodeord (degree-balanced
//      gather waves: each wave's 4 nodes have near-equal trip counts)
// ---------------------------------------------------------------------------
__global__ __launch_bounds__(BNW) void k_binB(const int* __restrict__ gcnt,
                                              const int* __restrict__ csrbase,
                                              const int* __restrict__ buck,
                                              int* __restrict__ rp,
                                              int* __restrict__ csr,
                                              int* __restrict__ nodeord) {
    int b = blockIdx.x;
    int tid = threadIdx.x;
    __shared__ int hist[BNW * NSL];   // (node,slice) histogram, then cursors
    __shared__ int part[BNW];         // scan scratch
    __shared__ int dhist[256];        // degree histogram -> class bases
    int n = gcnt[b];
    if (n > BCAP) n = BCAP;
    int base = csrbase[b];
    const int* bb = buck + (size_t)b * BCAP;

    for (int i = tid; i < BNW * NSL; i += BNW) hist[i] = 0;
    if (tid < 256) dhist[tid] = 0;
    __syncthreads();
    for (int i = tid; i < n; i += BNW) {
        int en = bb[i];
        atomicAdd(&hist[((en & (BNW - 1)) << 3) | ((en >> BSH) >> 14)], 1);
    }
    __syncthreads();

    // per-node degree + block scan -> rp
    int c0 = tid * NSL;
    int deg = 0;
#pragma unroll
    for (int q = 0; q < NSL; ++q) deg += hist[c0 + q];
    part[tid] = deg;
    __syncthreads();
    for (int off = 1; off < BNW; off <<= 1) {
        int t = (tid >= off) ? part[tid - off] : 0;
        __syncthreads();
        part[tid] += t;
        __syncthreads();
    }
    int excl = part[tid] - deg;
    int node = (b << BSH) + tid;
    if (node < NN) rp[node] = base + excl;

    // absolute cursors (node-major, slice-minor)
    int run = base + excl;
#pragma unroll
    for (int q = 0; q < NSL; ++q) { int h = hist[c0 + q]; hist[c0 + q] = run; run += h; }

    // degree-class position (order within class arbitrary)
    int dc = deg > 255 ? 255 : deg;
    int mypos = atomicAdd(&dhist[dc], 1);
    __syncthreads();

    // csr scatter (slice-ordered within each node)
    for (int i = tid; i < n; i += BNW) {
        int en = bb[i];
        int s = en >> BSH;
        int p = atomicAdd(&hist[((en & (BNW - 1)) << 3) | (s >> 14)], 1);
        csr[p] = s;
    }

    // exclusive scan of dhist via part[0..255]
    if (tid < 256) part[tid] = dhist[tid];
    __syncthreads();
    for (int off = 1; off < 256; off <<= 1) {
        int t = (tid < 256 && tid >= off) ? part[tid - off] : 0;
        __syncthreads();
        if (tid < 256) part[tid] += t;
        __syncthreads();
    }
    int dbase_val = (tid < 256) ? (part[tid] - dhist[tid]) : 0;
    __syncthreads();
    if (tid < 256) dhist[tid] = dbase_val;
    __syncthreads();

    nodeord[(b << BSH) + dhist[dc] + mypos] = node;
}

// ---------------------------------------------------------------------------
// f32 -> bf16 conversion (8 elems/thread)
// ---------------------------------------------------------------------------
__global__ void k_cvt_bf16(const float* __restrict__ in, u16* __restrict__ out) {
    int i = blockIdx.x * blockDim.x + threadIdx.x;
    size_t base = (size_t)i * 8;
    if (base >= (size_t)NN * C) return;
    float4 a = *reinterpret_cast<const float4*>(in + base);
    float4 b = *reinterpret_cast<const float4*>(in + base + 4);
    u16 o[8] = { f2bf(a.x), f2bf(a.y), f2bf(a.z), f2bf(a.w),
                 f2bf(b.x), f2bf(b.y), f2bf(b.z), f2bf(b.w) };
    *reinterpret_cast<short8*>(out + base) = *reinterpret_cast<const short8*>(o);
}

// ---------------------------------------------------------------------------
// Pack [W_rel; W_root] (256x128 f32) into per-lane MFMA B-fragment order, bf16.
// ---------------------------------------------------------------------------
__global__ void k_pack_w(const float* __restrict__ W_rel,
                         const float* __restrict__ W_root,
                         u16* __restrict__ Bp) {
    int t = blockIdx.x * blockDim.x + threadIdx.x;   // 0..4095
    if (t >= 4096) return;
    int lane = t & 63;
    int nfrag = (t >> 6) & 7;
    int kk = t >> 9;
    int col = nfrag * 16 + (lane & 15);
    int k0 = kk * 32 + (lane >> 4) * 8;
    u16 vals[8];
#pragma unroll
    for (int j = 0; j < 8; ++j) {
        int k = k0 + j;
        float w = (k < C) ? W_rel[k * C + col] : W_root[(k - C) * C + col];
        vals[j] = f2bf(w);
    }
    *reinterpret_cast<short8*>(Bp + (size_t)t * 8) = *reinterpret_cast<const short8*>(vals);
}

// ---------------------------------------------------------------------------
// Gather-aggregate (bf16): agg[i] = sum_{j in in(i)} h[j].  16 lanes/node,
// nodes processed in degree-sorted order (nodeord) for wave balance.
// ---------------------------------------------------------------------------
__global__ void k_gather(const u16* __restrict__ h, const int* __restrict__ rp,
                         const int* __restrict__ csr, const int* __restrict__ nodeord,
                         u16* __restrict__ agg) {
    int t = blockIdx.x * blockDim.x + threadIdx.x;
    int g = t >> 4;
    if (g >= NODR) return;
    int node = nodeord[g];
    if (node >= NN) return;
    int seg = (t & 15) * 8;   // element offset within row
    int beg = rp[node], end = rp[node + 1];
    float acc[8] = {};
    for (int j = beg; j < end; ++j) {
        int s = csr[j];
        short8 v = *reinterpret_cast<const short8*>(h + (size_t)s * C + seg);
#pragma unroll
        for (int q = 0; q < 8; ++q) acc[q] += bf2f((u16)v[q]);
    }
    u16 o[8];
#pragma unroll
    for (int q = 0; q < 8; ++q) o[q] = f2bf(acc[q]);
    *reinterpret_cast<short8*>(agg + (size_t)node * C + seg) = *reinterpret_cast<const short8*>(o);
}

// ---------------------------------------------------------------------------
// MFMA transform: out = [relu]( [agg|h] @ [W_rel;W_root] + b ), bf16 in/out.
// Block = 4 waves x 32 rows = 128 nodes; each wave does 2 A-frag sets per
// B-frag load (halves B traffic/row).  In-place safe: a wave reads only its
// own 32 rows before its epilogue writes them; clamped-lane reads only feed
// invalid D rows.
// ---------------------------------------------------------------------------
template <bool RELU>
__global__ __launch_bounds__(256) void k_transform_mfma(
    const u16* __restrict__ agg, const u16* __restrict__ h,
    const u16* __restrict__ Bp, const float* __restrict__ bias,
    u16* __restrict__ out) {
    int wave = threadIdx.x >> 6;
    int lane = threadIdx.x & 63;
    int row0 = blockIdx.x * 128 + wave * 32;
    int r0 = row0 + (lane & 15);
    int r1 = r0 + 16;
    int r0c = r0 < NN ? r0 : NN - 1;
    int r1c = r1 < NN ? r1 : NN - 1;
    int koff = (lane >> 4) * 8;

    f32x4 acc0[8] = {};
    f32x4 acc1[8] = {};
#pragma unroll
    for (int kk = 0; kk < 8; ++kk) {
        const u16* srcb = (kk < 4) ? agg : h;
        int kbase = (kk & 3) * 32 + koff;
        bf16x8 a0 = *reinterpret_cast<const bf16x8*>(srcb + (size_t)r0c * C + kbase);
        bf16x8 a1 = *reinterpret_cast<const bf16x8*>(srcb + (size_t)r1c * C + kbase);
        const u16* bp = Bp + ((size_t)kk * 8 * 64 + lane) * 8;
#pragma unroll
        for (int n = 0; n < 8; ++n) {
            bf16x8 bfr = *reinterpret_cast<const bf16x8*>(bp + (size_t)n * 64 * 8);
            acc0[n] = __builtin_amdgcn_mfma_f32_16x16x32_bf16(a0, bfr, acc0[n], 0, 0, 0);
            acc1[n] = __builtin_amdgcn_mfma_f32_16x16x32_bf16(a1, bfr, acc1[n], 0, 0, 0);
        }
    }
    int colbase = lane & 15;
    int rowe0 = row0 + (lane >> 4) * 4;
#pragma unroll
    for (int n = 0; n < 8; ++n) {
        int col = n * 16 + colbase;
        float bb = bias[col];
#pragma unroll
        for (int r = 0; r < 4; ++r) {
            int ro = rowe0 + r;
            if (ro < NN) {
                float v = acc0[n][r] + bb;
                if (RELU) v = fmaxf(v, 0.0f);
                out[(size_t)ro * C + col] = f2bf(v);
            }
            int ro1 = ro + 16;
            if (ro1 < NN) {
                float v = acc1[n][r] + bb;
                if (RELU) v = fmaxf(v, 0.0f);
                out[(size_t)ro1 * C + col] = f2bf(v);
            }
        }
    }
}

// ---------------------------------------------------------------------------
// Graph boundaries via binary search (batch is sorted), then fused pool+linear.
// ---------------------------------------------------------------------------
__global__ void k_gbounds(const int* __restrict__ batch, int* __restrict__ gstart) {
    int g = blockIdx.x * blockDim.x + threadIdx.x;
    if (g > NG) return;
    int lo = 0, hi = NN;
    while (lo < hi) { int mid = (lo + hi) >> 1; if (batch[mid] < g) lo = mid + 1; else hi = mid; }
    gstart[g] = lo;
}

__global__ void k_pool_final(const u16* __restrict__ h, const int* __restrict__ gstart,
                             const float* __restrict__ W_lin, const float* __restrict__ b_lin,
                             float* __restrict__ out) {
    int g = blockIdx.x;
    int c = threadIdx.x;  // 128 threads
    int s = gstart[g], e = gstart[g + 1];
    float acc = 0.0f;
    for (int i = s; i < e; ++i) acc += bf2f(h[(size_t)i * C + c]);
    __shared__ float sp[C];
    float cnt = (float)max(e - s, 1);
    sp[c] = acc / cnt;
    __syncthreads();
    if (c < OC) {
        float o = b_lin[c];
#pragma unroll 8
        for (int k = 0; k < C; ++k) o += sp[k] * W_lin[k * OC + c];
        out[g * OC + c] = o;
    }
}

extern "C" void kernel_launch(void* const* d_in, const int* in_sizes, int n_in,
                              void* d_out, int out_size, void* d_ws, size_t ws_size,
                              hipStream_t stream) {
    const float* x       = (const float*)d_in[0];
    const int*   eidx    = (const int*)d_in[1];
    const int*   batch   = (const int*)d_in[2];
    const float* W1_rel  = (const float*)d_in[3];
    const float* b1      = (const float*)d_in[4];
    const float* W1_root = (const float*)d_in[5];
    const float* W2_rel  = (const float*)d_in[6];
    const float* b2      = (const float*)d_in[7];
    const float* W2_root = (const float*)d_in[8];
    const float* W3_rel  = (const float*)d_in[9];
    const float* b3      = (const float*)d_in[10];
    const float* W3_root = (const float*)d_in[11];
    const float* W_lin   = (const float*)d_in[12];
    const float* b_lin   = (const float*)d_in[13];
    float* out = (float*)d_out;

    const int* src = eidx;
    const int* dst = eidx + NE;

    // Workspace layout
    u16* xb   = (u16*)d_ws;                       // NN*C bf16
    u16* agg  = xb + (size_t)NN * C;              // NN*C bf16
    u16* hbuf = agg + (size_t)NN * C;             // NN*C bf16
    u16* Bp   = hbuf + (size_t)NN * C;            // 3 * 32768 bf16
    int* rp      = (int*)(Bp + 3 * 32768);        // NN+1
    int* csr     = rp + NN + 1;                   // NE
    int* buck    = csr + NE;                      // BK*BCAP
    int* gcnt    = buck + (size_t)BK * BCAP;      // BK
    int* csrbase = gcnt + BK;                     // BK
    int* nodeord = csrbase + BK;                  // NODR
    int* gstart  = nodeord + NODR;                // NG+1

    const int gb = (NODR * 16) / 256;             // gather blocks (16 lanes/node)
    const int tb = (NN + 127) / 128;              // transform blocks (128 rows)
    const int cvtb = ((NN * C / 8) + 255) / 256;

    // ---- Bucketed CSR build (shared by all 3 layers) ----
    hipMemsetAsync(gcnt, 0, BK * sizeof(int), stream);
    k_binA<<<ABLK, 256, 0, stream>>>(src, dst, gcnt, buck);
    k_binscan<<<1, 256, 0, stream>>>(gcnt, csrbase, rp);
    k_binB<<<BK, BNW, 0, stream>>>(gcnt, csrbase, buck, rp, csr, nodeord);

    // ---- Precompute: x->bf16, packed weights, graph bounds ----
    k_cvt_bf16<<<cvtb, 256, 0, stream>>>(x, xb);
    k_pack_w<<<16, 256, 0, stream>>>(W1_rel, W1_root, Bp);
    k_pack_w<<<16, 256, 0, stream>>>(W2_rel, W2_root, Bp + 32768);
    k_pack_w<<<16, 256, 0, stream>>>(W3_rel, W3_root, Bp + 2 * 32768);
    k_gbounds<<<3, 256, 0, stream>>>(batch, gstart);

    // ---- Layer 1 ----
    k_gather<<<gb, 256, 0, stream>>>(xb, rp, csr, nodeord, agg);
    k_transform_mfma<true><<<tb, 256, 0, stream>>>(agg, xb, Bp, b1, hbuf);

    // ---- Layer 2 (in-place) ----
    k_gather<<<gb, 256, 0, stream>>>(hbuf, rp, csr, nodeord, agg);
    k_transform_mfma<true><<<tb, 256, 0, stream>>>(agg, hbuf, Bp + 32768, b2, hbuf);

    // ---- Layer 3 (no relu, in-place) ----
    k_gather<<<gb, 256, 0, stream>>>(hbuf, rp, csr, nodeord, agg);
    k_transform_mfma<false><<<tb, 256, 0, stream>>>(agg, hbuf, Bp + 2 * 32768, b3, hbuf);

    // ---- Fused pool + final linear ----
    k_pool_final<<<NG, C, 0, stream>>>(hbuf, gstart, W_lin, b_lin, out);
}

// Round 7
// 418.252 us; speedup vs baseline: 1.2735x; 1.2735x over previous
//
#include <hip/hip_runtime.h>

static constexpr int NN = 100000;   // nodes
static constexpr int NE = 1600000;  // edges
static constexpr int C  = 128;      // feature dim
static constexpr int OC = 10;       // output classes
static constexpr int NG = 512;      // graphs

// Bucketed CSR build parameters
static constexpr int BSH  = 9;                         // 512 nodes per bucket
static constexpr int BNW  = 1 << BSH;                  // 512
static constexpr int BK   = (NN + BNW - 1) / BNW;      // 196 buckets
static constexpr int BCAP = 12288;                     // slab capacity (avg ~8163)
static constexpr int EPB  = 8192;                      // edges per binA block
static constexpr int ABLK = (NE + EPB - 1) / EPB;      // 196

typedef unsigned short u16;
typedef __attribute__((ext_vector_type(8))) short short8;   // 8 bf16 = 16B
typedef __attribute__((ext_vector_type(8))) short bf16x8;   // MFMA A/B frag
typedef __attribute__((ext_vector_type(4))) float f32x4;    // MFMA C/D frag

__device__ __forceinline__ float bf2f(u16 u) {
    union { float f; unsigned int u32; } v; v.u32 = ((unsigned int)u) << 16; return v.f;
}
__device__ __forceinline__ u16 f2bf(float f) {
    union { float f; unsigned int u; } v; v.f = f;
    unsigned int u = v.u;
    unsigned int r = u + 0x7FFF + ((u >> 16) & 1);   // RNE
    return (u16)(r >> 16);
}

// ---------------------------------------------------------------------------
// Phase A: bin edges into BK buckets by dst>>BSH (L2-local slab writes).
// ---------------------------------------------------------------------------
__global__ __launch_bounds__(256) void k_binA(const int* __restrict__ src,
                                              const int* __restrict__ dst,
                                              int* __restrict__ gcnt,
                                              int* __restrict__ buck) {
    __shared__ int cnt[BK];
    __shared__ int curs[BK];
    int tid = threadIdx.x;
    for (int i = tid; i < BK; i += 256) cnt[i] = 0;
    __syncthreads();
    int e0 = blockIdx.x * EPB;
    for (int i = tid; i < EPB; i += 256) {
        int e = e0 + i;
        if (e < NE) atomicAdd(&cnt[dst[e] >> BSH], 1);
    }
    __syncthreads();
    for (int i = tid; i < BK; i += 256) {
        int c = cnt[i];
        int gb = (c > 0) ? atomicAdd(&gcnt[i], c) : 0;
        curs[i] = i * BCAP + gb;
    }
    __syncthreads();
    for (int i = tid; i < EPB; i += 256) {
        int e = e0 + i;
        if (e < NE) {
            int d = dst[e];
            int b = d >> BSH;
            int p = atomicAdd(&curs[b], 1);
            if (p < (b + 1) * BCAP)
                buck[p] = (src[e] << BSH) | (d & (BNW - 1));
        }
    }
}

// ---------------------------------------------------------------------------
// Exclusive scan of bucket counts -> per-bucket CSR base.  Also rp[NN]=NE.
// ---------------------------------------------------------------------------
__global__ void k_binscan(const int* __restrict__ gcnt, int* __restrict__ csrbase,
                          int* __restrict__ rp) {
    __shared__ int buf[256];
    int tid = threadIdx.x;
    int v = (tid < BK) ? gcnt[tid] : 0;
    buf[tid] = v;
    __syncthreads();
    for (int off = 1; off < 256; off <<= 1) {
        int t = (tid >= off) ? buf[tid - off] : 0;
        __syncthreads();
        buf[tid] += t;
        __syncthreads();
    }
    if (tid < BK) csrbase[tid] = buf[tid] - v;
    if (tid == 0) rp[NN] = NE;
}

// ---------------------------------------------------------------------------
// Phase B: one block per bucket.  LDS histogram over the bucket's 512 nodes,
// LDS scan -> rp slice, then LDS-cursor scatter into the bucket's contiguous
// CSR window (single block -> L2-local writes).
// ---------------------------------------------------------------------------
__global__ __launch_bounds__(BNW) void k_binB(const int* __restrict__ gcnt,
                                              const int* __restrict__ csrbase,
                                              const int* __restrict__ buck,
                                              int* __restrict__ rp,
                                              int* __restrict__ csr) {
    int b = blockIdx.x;
    int tid = threadIdx.x;
    __shared__ int hist[BNW];     // histogram, then cursor
    __shared__ int scanbuf[BNW];
    int n = gcnt[b];
    if (n > BCAP) n = BCAP;
    int base = csrbase[b];
    const int* bb = buck + (size_t)b * BCAP;

    hist[tid] = 0;
    __syncthreads();
    for (int i = tid; i < n; i += BNW) atomicAdd(&hist[bb[i] & (BNW - 1)], 1);
    __syncthreads();

    int v = hist[tid];
    scanbuf[tid] = v;
    __syncthreads();
    for (int off = 1; off < BNW; off <<= 1) {
        int t = (tid >= off) ? scanbuf[tid - off] : 0;
        __syncthreads();
        scanbuf[tid] += t;
        __syncthreads();
    }
    int excl = scanbuf[tid] - v;
    int node = (b << BSH) + tid;
    if (node < NN) rp[node] = base + excl;
    __syncthreads();
    hist[tid] = base + excl;      // cursor
    __syncthreads();
    for (int i = tid; i < n; i += BNW) {
        int en = bb[i];
        int p = atomicAdd(&hist[en & (BNW - 1)], 1);
        csr[p] = en >> BSH;
    }
}

// ---------------------------------------------------------------------------
// f32 -> bf16 conversion (8 elems/thread)
// ---------------------------------------------------------------------------
__global__ void k_cvt_bf16(const float* __restrict__ in, u16* __restrict__ out) {
    int i = blockIdx.x * blockDim.x + threadIdx.x;
    size_t base = (size_t)i * 8;
    if (base >= (size_t)NN * C) return;
    float4 a = *reinterpret_cast<const float4*>(in + base);
    float4 b = *reinterpret_cast<const float4*>(in + base + 4);
    u16 o[8] = { f2bf(a.x), f2bf(a.y), f2bf(a.z), f2bf(a.w),
                 f2bf(b.x), f2bf(b.y), f2bf(b.z), f2bf(b.w) };
    *reinterpret_cast<short8*>(out + base) = *reinterpret_cast<const short8*>(o);
}

// ---------------------------------------------------------------------------
// Pack [W_rel; W_root] (256x128 f32) into per-lane MFMA B-fragment order, bf16.
// ---------------------------------------------------------------------------
__global__ void k_pack_w(const float* __restrict__ W_rel,
                         const float* __restrict__ W_root,
                         u16* __restrict__ Bp) {
    int t = blockIdx.x * blockDim.x + threadIdx.x;   // 0..4095
    if (t >= 4096) return;
    int lane = t & 63;
    int nfrag = (t >> 6) & 7;
    int kk = t >> 9;
    int col = nfrag * 16 + (lane & 15);
    int k0 = kk * 32 + (lane >> 4) * 8;
    u16 vals[8];
#pragma unroll
    for (int j = 0; j < 8; ++j) {
        int k = k0 + j;
        float w = (k < C) ? W_rel[k * C + col] : W_root[(k - C) * C + col];
        vals[j] = f2bf(w);
    }
    *reinterpret_cast<short8*>(Bp + (size_t)t * 8) = *reinterpret_cast<const short8*>(vals);
}

// ---------------------------------------------------------------------------
// Gather-aggregate (bf16): agg[i] = sum_{j in in(i)} h[j].  16 lanes/node.
// Edge loop unrolled x4: 4 independent index + feature loads in flight per
// thread (MLP 1 -> 4) to hide L2/L3 latency.
// ---------------------------------------------------------------------------
__global__ void k_gather(const u16* __restrict__ h, const int* __restrict__ rp,
                         const int* __restrict__ csr, u16* __restrict__ agg) {
    int t = blockIdx.x * blockDim.x + threadIdx.x;
    int node = t >> 4;
    if (node >= NN) return;
    int seg = (t & 15) * 8;   // element offset within row
    int beg = rp[node], end = rp[node + 1];
    float acc[8] = {};
    int j = beg;
    for (; j + 4 <= end; j += 4) {
        int s0 = csr[j];
        int s1 = csr[j + 1];
        int s2 = csr[j + 2];
        int s3 = csr[j + 3];
        short8 v0 = *reinterpret_cast<const short8*>(h + (size_t)s0 * C + seg);
        short8 v1 = *reinterpret_cast<const short8*>(h + (size_t)s1 * C + seg);
        short8 v2 = *reinterpret_cast<const short8*>(h + (size_t)s2 * C + seg);
        short8 v3 = *reinterpret_cast<const short8*>(h + (size_t)s3 * C + seg);
#pragma unroll
        for (int q = 0; q < 8; ++q) {
            acc[q] += bf2f((u16)v0[q]);
            acc[q] += bf2f((u16)v1[q]);
            acc[q] += bf2f((u16)v2[q]);
            acc[q] += bf2f((u16)v3[q]);
        }
    }
    for (; j < end; ++j) {
        int s = csr[j];
        short8 v = *reinterpret_cast<const short8*>(h + (size_t)s * C + seg);
#pragma unroll
        for (int q = 0; q < 8; ++q) acc[q] += bf2f((u16)v[q]);
    }
    u16 o[8];
#pragma unroll
    for (int q = 0; q < 8; ++q) o[q] = f2bf(acc[q]);
    *reinterpret_cast<short8*>(agg + (size_t)node * C + seg) = *reinterpret_cast<const short8*>(o);
}

// ---------------------------------------------------------------------------
// MFMA transform: out = [relu]( [agg|h] @ [W_rel;W_root] + b ), bf16 in/out.
// Block = 4 waves x 16 rows = 64 nodes; wave computes 16 x 128.
// Safe in-place (out == h): each block only reads/writes its own rows.
// ---------------------------------------------------------------------------
template <bool RELU>
__global__ __launch_bounds__(256) void k_transform_mfma(
    const u16* __restrict__ agg, const u16* __restrict__ h,
    const u16* __restrict__ Bp, const float* __restrict__ bias,
    u16* __restrict__ out) {
    int wave = threadIdx.x >> 6;
    int lane = threadIdx.x & 63;
    int row0 = blockIdx.x * 64 + wave * 16;
    int arow = row0 + (lane & 15);
    int rclamp = arow < NN ? arow : NN - 1;
    int koff = (lane >> 4) * 8;

    f32x4 acc[8] = {};
#pragma unroll
    for (int kk = 0; kk < 8; ++kk) {
        bf16x8 a;
        if (kk < 4) {
            a = *reinterpret_cast<const bf16x8*>(agg + (size_t)rclamp * C + kk * 32 + koff);
        } else {
            a = *reinterpret_cast<const bf16x8*>(h + (size_t)rclamp * C + (kk - 4) * 32 + koff);
        }
        const u16* bp = Bp + ((size_t)kk * 8 * 64 + lane) * 8;
#pragma unroll
        for (int n = 0; n < 8; ++n) {
            bf16x8 b = *reinterpret_cast<const bf16x8*>(bp + (size_t)n * 64 * 8);
            acc[n] = __builtin_amdgcn_mfma_f32_16x16x32_bf16(a, b, acc[n], 0, 0, 0);
        }
    }
    int colbase = lane & 15;
    int rowe = row0 + (lane >> 4) * 4;
#pragma unroll
    for (int n = 0; n < 8; ++n) {
        int col = n * 16 + colbase;
        float bb = bias[col];
#pragma unroll
        for (int r = 0; r < 4; ++r) {
            int ro = rowe + r;
            if (ro < NN) {
                float v = acc[n][r] + bb;
                if (RELU) v = fmaxf(v, 0.0f);
                out[(size_t)ro * C + col] = f2bf(v);
            }
        }
    }
}

// ---------------------------------------------------------------------------
// Graph boundaries via binary search (batch is sorted), then fused pool+linear.
// ---------------------------------------------------------------------------
__global__ void k_gbounds(const int* __restrict__ batch, int* __restrict__ gstart) {
    int g = blockIdx.x * blockDim.x + threadIdx.x;
    if (g > NG) return;
    int lo = 0, hi = NN;
    while (lo < hi) { int mid = (lo + hi) >> 1; if (batch[mid] < g) lo = mid + 1; else hi = mid; }
    gstart[g] = lo;
}

__global__ void k_pool_final(const u16* __restrict__ h, const int* __restrict__ gstart,
                             const float* __restrict__ W_lin, const float* __restrict__ b_lin,
                             float* __restrict__ out) {
    int g = blockIdx.x;
    int c = threadIdx.x;  // 128 threads
    int s = gstart[g], e = gstart[g + 1];
    float acc = 0.0f;
    for (int i = s; i < e; ++i) acc += bf2f(h[(size_t)i * C + c]);
    __shared__ float sp[C];
    float cnt = (float)max(e - s, 1);
    sp[c] = acc / cnt;
    __syncthreads();
    if (c < OC) {
        float o = b_lin[c];
#pragma unroll 8
        for (int k = 0; k < C; ++k) o += sp[k] * W_lin[k * OC + c];
        out[g * OC + c] = o;
    }
}

extern "C" void kernel_launch(void* const* d_in, const int* in_sizes, int n_in,
                              void* d_out, int out_size, void* d_ws, size_t ws_size,
                              hipStream_t stream) {
    const float* x       = (const float*)d_in[0];
    const int*   eidx    = (const int*)d_in[1];
    const int*   batch   = (const int*)d_in[2];
    const float* W1_rel  = (const float*)d_in[3];
    const float* b1      = (const float*)d_in[4];
    const float* W1_root = (const float*)d_in[5];
    const float* W2_rel  = (const float*)d_in[6];
    const float* b2      = (const float*)d_in[7];
    const float* W2_root = (const float*)d_in[8];
    const float* W3_rel  = (const float*)d_in[9];
    const float* b3      = (const float*)d_in[10];
    const float* W3_root = (const float*)d_in[11];
    const float* W_lin   = (const float*)d_in[12];
    const float* b_lin   = (const float*)d_in[13];
    float* out = (float*)d_out;

    const int* src = eidx;
    const int* dst = eidx + NE;

    // Workspace layout
    u16* xb   = (u16*)d_ws;                       // NN*C bf16
    u16* hb   = xb + (size_t)NN * C;              // NN*C bf16
    u16* aggb = hb + (size_t)NN * C;              // NN*C bf16
    u16* Bp   = aggb + (size_t)NN * C;            // 3 * 32768 bf16
    int* rp      = (int*)(Bp + 3 * 32768);        // NN+1
    int* csr     = rp + NN + 1;                   // NE
    int* buck    = csr + NE;                      // BK*BCAP
    int* gcnt    = buck + (size_t)BK * BCAP;      // BK
    int* csrbase = gcnt + BK;                     // BK
    int* gstart  = csrbase + BK;                  // NG+1

    const int gb = (NN * 16 + 255) / 256;         // gather blocks (16 lanes/node)
    const int tb = (NN + 63) / 64;                // transform blocks
    const int cvtb = ((NN * C / 8) + 255) / 256;

    // ---- Bucketed CSR build (shared by all 3 layers) ----
    hipMemsetAsync(gcnt, 0, BK * sizeof(int), stream);
    k_binA<<<ABLK, 256, 0, stream>>>(src, dst, gcnt, buck);
    k_binscan<<<1, 256, 0, stream>>>(gcnt, csrbase, rp);
    k_binB<<<BK, BNW, 0, stream>>>(gcnt, csrbase, buck, rp, csr);

    // ---- Precompute: x->bf16, packed weights, graph bounds ----
    k_cvt_bf16<<<cvtb, 256, 0, stream>>>(x, xb);
    k_pack_w<<<16, 256, 0, stream>>>(W1_rel, W1_root, Bp);
    k_pack_w<<<16, 256, 0, stream>>>(W2_rel, W2_root, Bp + 32768);
    k_pack_w<<<16, 256, 0, stream>>>(W3_rel, W3_root, Bp + 2 * 32768);
    k_gbounds<<<3, 256, 0, stream>>>(batch, gstart);

    // ---- Layer 1 ----
    k_gather<<<gb, 256, 0, stream>>>(xb, rp, csr, aggb);
    k_transform_mfma<true><<<tb, 256, 0, stream>>>(aggb, xb, Bp, b1, hb);

    // ---- Layer 2 (in-place) ----
    k_gather<<<gb, 256, 0, stream>>>(hb, rp, csr, aggb);
    k_transform_mfma<true><<<tb, 256, 0, stream>>>(aggb, hb, Bp + 32768, b2, hb);

    // ---- Layer 3 (no relu, in-place) ----
    k_gather<<<gb, 256, 0, stream>>>(hb, rp, csr, aggb);
    k_transform_mfma<false><<<tb, 256, 0, stream>>>(aggb, hb, Bp + 2 * 32768, b3, hb);

    // ---- Fused pool + final linear ----
    k_pool_final<<<NG, C, 0, stream>>>(hb, gstart, W_lin, b_lin, out);
}

// Round 8
// 363.086 us; speedup vs baseline: 1.4670x; 1.1519x over previous
//
#include <hip/hip_runtime.h>

static constexpr int NN = 100000;   // nodes
static constexpr int NE = 1600000;  // edges
static constexpr int C  = 128;      // feature dim
static constexpr int OC = 10;       // output classes
static constexpr int NG = 512;      // graphs

// Bucketed CSR build parameters
static constexpr int BSH  = 9;                         // 512 nodes per bucket
static constexpr int BNW  = 1 << BSH;                  // 512
static constexpr int BK   = (NN + BNW - 1) / BNW;      // 196 buckets
static constexpr int BCAP = 12288;                     // slab capacity (avg ~8163)
static constexpr int EPB  = 8192;                      // edges per binA block
static constexpr int ABLK = (NE + EPB - 1) / EPB;      // 196

typedef unsigned short u16;
typedef __attribute__((ext_vector_type(8))) short short8;   // 8 bf16 = 16B
typedef __attribute__((ext_vector_type(8))) short bf16x8;   // MFMA A/B frag
typedef __attribute__((ext_vector_type(4))) float f32x4;    // MFMA C/D frag

__device__ __forceinline__ float bf2f(u16 u) {
    union { float f; unsigned int u32; } v; v.u32 = ((unsigned int)u) << 16; return v.f;
}
__device__ __forceinline__ u16 f2bf(float f) {
    union { float f; unsigned int u; } v; v.f = f;
    unsigned int u = v.u;
    unsigned int r = u + 0x7FFF + ((u >> 16) & 1);   // RNE
    return (u16)(r >> 16);
}

// ---------------------------------------------------------------------------
// Phase A: bin edges into BK buckets by dst>>BSH (L2-local slab writes).
// ---------------------------------------------------------------------------
__global__ __launch_bounds__(256) void k_binA(const int* __restrict__ src,
                                              const int* __restrict__ dst,
                                              int* __restrict__ gcnt,
                                              int* __restrict__ buck) {
    __shared__ int cnt[BK];
    __shared__ int curs[BK];
    int tid = threadIdx.x;
    for (int i = tid; i < BK; i += 256) cnt[i] = 0;
    __syncthreads();
    int e0 = blockIdx.x * EPB;
    for (int i = tid; i < EPB; i += 256) {
        int e = e0 + i;
        if (e < NE) atomicAdd(&cnt[dst[e] >> BSH], 1);
    }
    __syncthreads();
    for (int i = tid; i < BK; i += 256) {
        int c = cnt[i];
        int gb = (c > 0) ? atomicAdd(&gcnt[i], c) : 0;
        curs[i] = i * BCAP + gb;
    }
    __syncthreads();
    for (int i = tid; i < EPB; i += 256) {
        int e = e0 + i;
        if (e < NE) {
            int d = dst[e];
            int b = d >> BSH;
            int p = atomicAdd(&curs[b], 1);
            if (p < (b + 1) * BCAP)
                buck[p] = (src[e] << BSH) | (d & (BNW - 1));
        }
    }
}

// ---------------------------------------------------------------------------
// Exclusive scan of bucket counts -> per-bucket CSR base.  Also rp[NN]=NE.
// ---------------------------------------------------------------------------
__global__ void k_binscan(const int* __restrict__ gcnt, int* __restrict__ csrbase,
                          int* __restrict__ rp) {
    __shared__ int buf[256];
    int tid = threadIdx.x;
    int v = (tid < BK) ? gcnt[tid] : 0;
    buf[tid] = v;
    __syncthreads();
    for (int off = 1; off < 256; off <<= 1) {
        int t = (tid >= off) ? buf[tid - off] : 0;
        __syncthreads();
        buf[tid] += t;
        __syncthreads();
    }
    if (tid < BK) csrbase[tid] = buf[tid] - v;
    if (tid == 0) rp[NN] = NE;
}

// ---------------------------------------------------------------------------
// Phase B: one block per bucket.  LDS histogram over the bucket's 512 nodes,
// LDS scan -> rp slice, then LDS-cursor scatter into the bucket's contiguous
// CSR window (single block -> L2-local writes).
// ---------------------------------------------------------------------------
__global__ __launch_bounds__(BNW) void k_binB(const int* __restrict__ gcnt,
                                              const int* __restrict__ csrbase,
                                              const int* __restrict__ buck,
                                              int* __restrict__ rp,
                                              int* __restrict__ csr) {
    int b = blockIdx.x;
    int tid = threadIdx.x;
    __shared__ int hist[BNW];     // histogram, then cursor
    __shared__ int scanbuf[BNW];
    int n = gcnt[b];
    if (n > BCAP) n = BCAP;
    int base = csrbase[b];
    const int* bb = buck + (size_t)b * BCAP;

    hist[tid] = 0;
    __syncthreads();
    for (int i = tid; i < n; i += BNW) atomicAdd(&hist[bb[i] & (BNW - 1)], 1);
    __syncthreads();

    int v = hist[tid];
    scanbuf[tid] = v;
    __syncthreads();
    for (int off = 1; off < BNW; off <<= 1) {
        int t = (tid >= off) ? scanbuf[tid - off] : 0;
        __syncthreads();
        scanbuf[tid] += t;
        __syncthreads();
    }
    int excl = scanbuf[tid] - v;
    int node = (b << BSH) + tid;
    if (node < NN) rp[node] = base + excl;
    __syncthreads();
    hist[tid] = base + excl;      // cursor
    __syncthreads();
    for (int i = tid; i < n; i += BNW) {
        int en = bb[i];
        int p = atomicAdd(&hist[en & (BNW - 1)], 1);
        csr[p] = en >> BSH;
    }
}

// ---------------------------------------------------------------------------
// f32 -> bf16 conversion (8 elems/thread)
// ---------------------------------------------------------------------------
__global__ void k_cvt_bf16(const float* __restrict__ in, u16* __restrict__ out) {
    int i = blockIdx.x * blockDim.x + threadIdx.x;
    size_t base = (size_t)i * 8;
    if (base >= (size_t)NN * C) return;
    float4 a = *reinterpret_cast<const float4*>(in + base);
    float4 b = *reinterpret_cast<const float4*>(in + base + 4);
    u16 o[8] = { f2bf(a.x), f2bf(a.y), f2bf(a.z), f2bf(a.w),
                 f2bf(b.x), f2bf(b.y), f2bf(b.z), f2bf(b.w) };
    *reinterpret_cast<short8*>(out + base) = *reinterpret_cast<const short8*>(o);
}

// ---------------------------------------------------------------------------
// Pack [W_rel; W_root] (256x128 f32) into per-lane MFMA B-fragment order, bf16.
// ---------------------------------------------------------------------------
__global__ void k_pack_w(const float* __restrict__ W_rel,
                         const float* __restrict__ W_root,
                         u16* __restrict__ Bp) {
    int t = blockIdx.x * blockDim.x + threadIdx.x;   // 0..4095
    if (t >= 4096) return;
    int lane = t & 63;
    int nfrag = (t >> 6) & 7;
    int kk = t >> 9;
    int col = nfrag * 16 + (lane & 15);
    int k0 = kk * 32 + (lane >> 4) * 8;
    u16 vals[8];
#pragma unroll
    for (int j = 0; j < 8; ++j) {
        int k = k0 + j;
        float w = (k < C) ? W_rel[k * C + col] : W_root[(k - C) * C + col];
        vals[j] = f2bf(w);
    }
    *reinterpret_cast<short8*>(Bp + (size_t)t * 8) = *reinterpret_cast<const short8*>(vals);
}

// ---------------------------------------------------------------------------
// Gather-aggregate (bf16): agg[i] = sum_{j in in(i)} h[j].  16 lanes/node.
// Edge loop unrolled x4 (4 loads in flight per thread).
// ---------------------------------------------------------------------------
__global__ void k_gather(const u16* __restrict__ h, const int* __restrict__ rp,
                         const int* __restrict__ csr, u16* __restrict__ agg) {
    int t = blockIdx.x * blockDim.x + threadIdx.x;
    int node = t >> 4;
    if (node >= NN) return;
    int seg = (t & 15) * 8;   // element offset within row
    int beg = rp[node], end = rp[node + 1];
    float acc[8] = {};
    int j = beg;
    for (; j + 4 <= end; j += 4) {
        int s0 = csr[j];
        int s1 = csr[j + 1];
        int s2 = csr[j + 2];
        int s3 = csr[j + 3];
        short8 v0 = *reinterpret_cast<const short8*>(h + (size_t)s0 * C + seg);
        short8 v1 = *reinterpret_cast<const short8*>(h + (size_t)s1 * C + seg);
        short8 v2 = *reinterpret_cast<const short8*>(h + (size_t)s2 * C + seg);
        short8 v3 = *reinterpret_cast<const short8*>(h + (size_t)s3 * C + seg);
#pragma unroll
        for (int q = 0; q < 8; ++q) {
            acc[q] += bf2f((u16)v0[q]);
            acc[q] += bf2f((u16)v1[q]);
            acc[q] += bf2f((u16)v2[q]);
            acc[q] += bf2f((u16)v3[q]);
        }
    }
    for (; j < end; ++j) {
        int s = csr[j];
        short8 v = *reinterpret_cast<const short8*>(h + (size_t)s * C + seg);
#pragma unroll
        for (int q = 0; q < 8; ++q) acc[q] += bf2f((u16)v[q]);
    }
    u16 o[8];
#pragma unroll
    for (int q = 0; q < 8; ++q) o[q] = f2bf(acc[q]);
    *reinterpret_cast<short8*>(agg + (size_t)node * C + seg) = *reinterpret_cast<const short8*>(o);
}

// ---------------------------------------------------------------------------
// MFMA transform: out = [relu]( [agg|h] @ [W_rel;W_root] + b ), bf16 in/out.
// Block = 4 waves x 16 rows = 64 nodes; wave computes 16 x 128.
// Safe in-place (out == h): each block only reads/writes its own rows.
// ---------------------------------------------------------------------------
template <bool RELU>
__global__ __launch_bounds__(256) void k_transform_mfma(
    const u16* __restrict__ agg, const u16* __restrict__ h,
    const u16* __restrict__ Bp, const float* __restrict__ bias,
    u16* __restrict__ out) {
    int wave = threadIdx.x >> 6;
    int lane = threadIdx.x & 63;
    int row0 = blockIdx.x * 64 + wave * 16;
    int arow = row0 + (lane & 15);
    int rclamp = arow < NN ? arow : NN - 1;
    int koff = (lane >> 4) * 8;

    f32x4 acc[8] = {};
#pragma unroll
    for (int kk = 0; kk < 8; ++kk) {
        bf16x8 a;
        if (kk < 4) {
            a = *reinterpret_cast<const bf16x8*>(agg + (size_t)rclamp * C + kk * 32 + koff);
        } else {
            a = *reinterpret_cast<const bf16x8*>(h + (size_t)rclamp * C + (kk - 4) * 32 + koff);
        }
        const u16* bp = Bp + ((size_t)kk * 8 * 64 + lane) * 8;
#pragma unroll
        for (int n = 0; n < 8; ++n) {
            bf16x8 b = *reinterpret_cast<const bf16x8*>(bp + (size_t)n * 64 * 8);
            acc[n] = __builtin_amdgcn_mfma_f32_16x16x32_bf16(a, b, acc[n], 0, 0, 0);
        }
    }
    int colbase = lane & 15;
    int rowe = row0 + (lane >> 4) * 4;
#pragma unroll
    for (int n = 0; n < 8; ++n) {
        int col = n * 16 + colbase;
        float bb = bias[col];
#pragma unroll
        for (int r = 0; r < 4; ++r) {
            int ro = rowe + r;
            if (ro < NN) {
                float v = acc[n][r] + bb;
                if (RELU) v = fmaxf(v, 0.0f);
                out[(size_t)ro * C + col] = f2bf(v);
            }
        }
    }
}

// ---------------------------------------------------------------------------
// Graph boundaries via binary search (batch is sorted), then fused pool+linear.
// ---------------------------------------------------------------------------
__global__ void k_gbounds(const int* __restrict__ batch, int* __restrict__ gstart) {
    int g = blockIdx.x * blockDim.x + threadIdx.x;
    if (g > NG) return;
    int lo = 0, hi = NN;
    while (lo < hi) { int mid = (lo + hi) >> 1; if (batch[mid] < g) lo = mid + 1; else hi = mid; }
    gstart[g] = lo;
}

// ---------------------------------------------------------------------------
// Fused mean-pool + final linear.  Block = 256 threads = 16 row-slots x 16
// col-segments; each thread strided-loads short8 (8 cols) -> one coalesced
// 4 KB transaction per iteration.  LDS tree-reduce over row-slots, then the
// 128x10 linear.
// ---------------------------------------------------------------------------
__global__ __launch_bounds__(256) void k_pool_final(
    const u16* __restrict__ h, const int* __restrict__ gstart,
    const float* __restrict__ W_lin, const float* __restrict__ b_lin,
    float* __restrict__ out) {
    int g = blockIdx.x;
    int rowslot = threadIdx.x >> 4;      // 0..15
    int seg = threadIdx.x & 15;          // 0..15 (8 cols each)
    int s = gstart[g], e = gstart[g + 1];

    float acc[8] = {};
    for (int i = s + rowslot; i < e; i += 16) {
        short8 v = *reinterpret_cast<const short8*>(h + (size_t)i * C + seg * 8);
#pragma unroll
        for (int q = 0; q < 8; ++q) acc[q] += bf2f((u16)v[q]);
    }

    __shared__ float red[16][C];         // 8 KB
#pragma unroll
    for (int q = 0; q < 8; ++q) red[rowslot][seg * 8 + q] = acc[q];
    __syncthreads();

    __shared__ float sp[C];
    if (threadIdx.x < C) {
        float sum = 0.0f;
#pragma unroll
        for (int r = 0; r < 16; ++r) sum += red[r][threadIdx.x];
        float cnt = (float)max(e - s, 1);
        sp[threadIdx.x] = sum / cnt;
    }
    __syncthreads();
    if (threadIdx.x < OC) {
        float o = b_lin[threadIdx.x];
#pragma unroll 8
        for (int k = 0; k < C; ++k) o += sp[k] * W_lin[k * OC + threadIdx.x];
        out[g * OC + threadIdx.x] = o;
    }
}

extern "C" void kernel_launch(void* const* d_in, const int* in_sizes, int n_in,
                              void* d_out, int out_size, void* d_ws, size_t ws_size,
                              hipStream_t stream) {
    const float* x       = (const float*)d_in[0];
    const int*   eidx    = (const int*)d_in[1];
    const int*   batch   = (const int*)d_in[2];
    const float* W1_rel  = (const float*)d_in[3];
    const float* b1      = (const float*)d_in[4];
    const float* W1_root = (const float*)d_in[5];
    const float* W2_rel  = (const float*)d_in[6];
    const float* b2      = (const float*)d_in[7];
    const float* W2_root = (const float*)d_in[8];
    const float* W3_rel  = (const float*)d_in[9];
    const float* b3      = (const float*)d_in[10];
    const float* W3_root = (const float*)d_in[11];
    const float* W_lin   = (const float*)d_in[12];
    const float* b_lin   = (const float*)d_in[13];
    float* out = (float*)d_out;

    const int* src = eidx;
    const int* dst = eidx + NE;

    // Workspace layout
    u16* xb   = (u16*)d_ws;                       // NN*C bf16
    u16* hb   = xb + (size_t)NN * C;              // NN*C bf16
    u16* aggb = hb + (size_t)NN * C;              // NN*C bf16
    u16* Bp   = aggb + (size_t)NN * C;            // 3 * 32768 bf16
    int* rp      = (int*)(Bp + 3 * 32768);        // NN+1
    int* csr     = rp + NN + 1;                   // NE
    int* buck    = csr + NE;                      // BK*BCAP
    int* gcnt    = buck + (size_t)BK * BCAP;      // BK
    int* csrbase = gcnt + BK;                     // BK
    int* gstart  = csrbase + BK;                  // NG+1

    const int gb = (NN * 16 + 255) / 256;         // gather blocks (16 lanes/node)
    const int tb = (NN + 63) / 64;                // transform blocks
    const int cvtb = ((NN * C / 8) + 255) / 256;

    // ---- Bucketed CSR build (shared by all 3 layers) ----
    hipMemsetAsync(gcnt, 0, BK * sizeof(int), stream);
    k_binA<<<ABLK, 256, 0, stream>>>(src, dst, gcnt, buck);
    k_binscan<<<1, 256, 0, stream>>>(gcnt, csrbase, rp);
    k_binB<<<BK, BNW, 0, stream>>>(gcnt, csrbase, buck, rp, csr);

    // ---- Precompute: x->bf16, packed weights, graph bounds ----
    k_cvt_bf16<<<cvtb, 256, 0, stream>>>(x, xb);
    k_pack_w<<<16, 256, 0, stream>>>(W1_rel, W1_root, Bp);
    k_pack_w<<<16, 256, 0, stream>>>(W2_rel, W2_root, Bp + 32768);
    k_pack_w<<<16, 256, 0, stream>>>(W3_rel, W3_root, Bp + 2 * 32768);
    k_gbounds<<<3, 256, 0, stream>>>(batch, gstart);

    // ---- Layer 1 ----
    k_gather<<<gb, 256, 0, stream>>>(xb, rp, csr, aggb);
    k_transform_mfma<true><<<tb, 256, 0, stream>>>(aggb, xb, Bp, b1, hb);

    // ---- Layer 2 (in-place) ----
    k_gather<<<gb, 256, 0, stream>>>(hb, rp, csr, aggb);
    k_transform_mfma<true><<<tb, 256, 0, stream>>>(aggb, hb, Bp + 32768, b2, hb);

    // ---- Layer 3 (no relu, in-place) ----
    k_gather<<<gb, 256, 0, stream>>>(hb, rp, csr, aggb);
    k_transform_mfma<false><<<tb, 256, 0, stream>>>(aggb, hb, Bp + 2 * 32768, b3, hb);

    // ---- Fused pool + final linear ----
    k_pool_final<<<NG, 256, 0, stream>>>(hb, gstart, W_lin, b_lin, out);
}